// Round 8
// baseline (297.752 us; speedup 1.0000x reference)
//
#include <hip/hip_runtime.h>

// FC_CPPN: per-pixel tiny MLP, ALL float32 (inputs, weights, output).
//  d_in[0]=x[N], [1]=y[N], [2]=r[N], [3]=z[N,8], [4]=W0[8,11], [5]=b0[8],
//  [6]=Wm[8,8], [7]=bm[8], [8]=Wo[3,8], [9]=bo[3], [10]=masks[3,4,2] (int)
// out: float32 [N,3]
//
// Scaled-state formulation: u_l = 2^l * out_l.
//   pre_l   = (Wm*2^-l) u_l + bm          (prep stores 3 scaled Wm copies)
//   u_{l+1} = u_l + 2^l * act(pre_l)       (2^l = 1,2,4 -> inline consts)
//   result  = sigmoid((Wo/8) u_3 + bo)
//
// ws float layout:
//   [0,88)    W0 (cols 0..7 pre-scaled by 1/Z_SCALE=0.1)
//   [88,96)   b0
//   [96,288)  Wm*2^-l for l=0,1,2 (64 floats each)
//   [288,296) bm
//   [296,320) Wo/8
//   [320,323) bo
// ws int layout: [384,408) funid[l*8 + natural_column] = activation 0..3
//
// R8: CONVOY theory. One-shot waves start in phase per CU -> all resident
// waves stall on their load burst simultaneously; no wave covers another's
// latency (VALUBusy pinned ~42%, lifetime 6.4k cy vs 2.2k cy issue). R1's
// loop failed NOT from occupancy but from a defeated double buffer
// (VGPR=44 can't hold cur+nxt+u+p=76 -> compiler re-issued loads, 3x issue
// time at 69% busy). Fix: unroll-2 double buffer (no copies), 2048 blocks
// (8/CU), sweep divides N exactly (4 iters, no tail), compute body = R0's
// proven code verbatim -> bit-identical numerics. Watch VGPR (~90-120 =
// buffer materialized; <=50 = defeated again).

__global__ void cppn_prep(const float* __restrict__ W0,
                          const float* __restrict__ b0,
                          const float* __restrict__ Wm,
                          const float* __restrict__ bm,
                          const float* __restrict__ Wo,
                          const float* __restrict__ bo,
                          const int* __restrict__ masks,
                          float* __restrict__ wf,
                          int* __restrict__ wi) {
    int t = threadIdx.x;
    if (t < 88) {
        int k = t % 11;
        wf[t] = W0[t] * (k < 8 ? 0.1f : 1.0f);      // fold z/Z_SCALE
    } else if (t < 96) {
        wf[t] = b0[t - 88];
    } else if (t < 288) {
        int j = t - 96;
        int l = j >> 6;                              // which scaled copy
        float s = (l == 0) ? 1.0f : (l == 1 ? 0.5f : 0.25f);
        wf[96 + j] = Wm[j & 63] * s;
    } else if (t < 296) {
        wf[t] = bm[t - 288];
    } else if (t < 320) {
        wf[t] = Wo[t - 296] * 0.125f;                // fold /8
    } else if (t < 323) {
        wf[t] = bo[t - 320];
    } else if (t < 323 + 24) {
        int j = t - 323;          // j = l*8 + f*2 + slot  (masks flat [3,4,2])
        // int64-masks hedge: valid int32 masks have every odd entry >= 1;
        // int64-as-int32 has all odd words == 0 (high words, little-endian).
        bool is64 = true;
        for (int q = 1; q < 24; q += 2) is64 = is64 && (masks[q] == 0);
        int c = is64 ? masks[2 * j] : masks[j];      // natural column 0..7
        int l = j >> 3;
        int f = (j & 7) >> 1;                        // activation id
        wi[384 + l * 8 + c] = f;
    }
}

#define PX 2   // pixels per thread per iteration
#define TPB 256
#define TILE (TPB * PX)

__device__ __forceinline__ void tile_load(const float* __restrict__ xb,
                                          const float* __restrict__ yb,
                                          const float* __restrict__ rb,
                                          const float4* __restrict__ zb,
                                          int i0, int n,
                                          float (&in)[PX][11]) {
#pragma unroll
    for (int px = 0; px < PX; ++px) {
        int i = i0 + px * TPB;
        if (i >= n) i = 0;               // clamp; stores are guarded
        float4 z0 = zb[2 * i];
        float4 z1 = zb[2 * i + 1];
        in[px][0] = z0.x; in[px][1] = z0.y; in[px][2] = z0.z; in[px][3] = z0.w;
        in[px][4] = z1.x; in[px][5] = z1.y; in[px][6] = z1.z; in[px][7] = z1.w;
        in[px][8]  = xb[i];
        in[px][9]  = yb[i];
        in[px][10] = rb[i];
    }
}

// Compute + store for one tile. Body is R0's proven 86us code, verbatim
// op order -> bit-identical numerics.
__device__ __forceinline__ void tile_compute(const float* __restrict__ wf,
                                             const int* __restrict__ fid,
                                             const float (&in)[PX][11],
                                             float* __restrict__ out,
                                             int i0, int n) {
    float u[PX][8];
#pragma unroll
    for (int h = 0; h < 8; ++h) {
#pragma unroll
        for (int px = 0; px < PX; ++px) {
            float acc = wf[88 + h];
#pragma unroll
            for (int k = 0; k < 11; ++k)
                acc = fmaf(wf[h * 11 + k], in[px][k], acc);
            u[px][h] = acc;
        }
    }

#pragma unroll
    for (int l = 0; l < 3; ++l) {
        const float* W = wf + 96 + 64 * l;            // Wm * 2^-l
        const float scale = (l == 0) ? 1.0f : (l == 1 ? 2.0f : 4.0f);
        float p[PX][8];
#pragma unroll
        for (int h = 0; h < 8; ++h) {
#pragma unroll
            for (int px = 0; px < PX; ++px) {
                float acc = wf[288 + h];
#pragma unroll
                for (int k = 0; k < 8; ++k)
                    acc = fmaf(W[h * 8 + k], u[px][k], acc);
                p[px][h] = acc;
            }
        }
#pragma unroll
        for (int h = 0; h < 8; ++h) {
            // wave-uniform activation id -> scalar branch, no divergence;
            // one branch serves PX pixels.
            int f = __builtin_amdgcn_readfirstlane(fid[l * 8 + h]);
            float v[PX];
            if (f == 0) {
#pragma unroll
                for (int px = 0; px < PX; ++px) v[px] = __sinf(p[px][h]);
            } else if (f == 1) {
#pragma unroll
                for (int px = 0; px < PX; ++px) {
                    float t = p[px][h];
                    v[px] = 0.3989422804014327f * __expf(-0.5f * t * t);
                }
            } else if (f == 2) {
#pragma unroll
                for (int px = 0; px < PX; ++px) {
                    // tanh(t) = 1 - 2/(e^{2t}+1); e=inf -> rcp=0 -> v=1 (safe)
                    float e = __expf(2.0f * p[px][h]);
                    v[px] = fmaf(-2.0f, __builtin_amdgcn_rcpf(e + 1.0f), 1.0f);
                }
            } else {
#pragma unroll
                for (int px = 0; px < PX; ++px) v[px] = p[px][h];
            }
#pragma unroll
            for (int px = 0; px < PX; ++px)
                u[px][h] = fmaf(scale, v[px], u[px][h]);   // inline-const scale
        }
    }

#pragma unroll
    for (int j = 0; j < 3; ++j) {
#pragma unroll
        for (int px = 0; px < PX; ++px) {
            float acc = wf[320 + j];
#pragma unroll
            for (int k = 0; k < 8; ++k)
                acc = fmaf(wf[296 + j * 8 + k], u[px][k], acc);
            float e = __expf(-acc);                        // sigmoid
            float v = __builtin_amdgcn_rcpf(1.0f + e);
            int i = i0 + px * TPB;
            if (i < n) out[3 * i + j] = v;
        }
    }
}

__global__ __launch_bounds__(256) void cppn_main(
    const float* __restrict__ xb,
    const float* __restrict__ yb,
    const float* __restrict__ rb,
    const float4* __restrict__ zb,         // 8 f32 per pixel = two float4
    const float* __restrict__ wf,          // ws floats (uniform -> s_load)
    const int* __restrict__ fid,           // funid base (ws ints + 384)
    float* __restrict__ out,
    int n, int sweep) {                    // sweep = gridDim.x * TILE
    int i0 = blockIdx.x * TILE + threadIdx.x;
    if (i0 >= n) return;

    // Unroll-2 software pipeline with register double buffer A/B.
    // Prefetch of tile t+1 is issued BEFORE compute of tile t; buffers
    // alternate by loop parity -> zero register copies (R1's killer).
    float A[PX][11], B[PX][11];
    tile_load(xb, yb, rb, zb, i0, n, A);
    for (;;) {
        tile_load(xb, yb, rb, zb, i0 + sweep, n, B);   // prefetch (clamped)
        tile_compute(wf, fid, A, out, i0, n);
        i0 += sweep;
        if (i0 >= n) break;
        tile_load(xb, yb, rb, zb, i0 + sweep, n, A);   // prefetch (clamped)
        tile_compute(wf, fid, B, out, i0, n);
        i0 += sweep;
        if (i0 >= n) break;
    }
}

extern "C" void kernel_launch(void* const* d_in, const int* in_sizes, int n_in,
                              void* d_out, int out_size, void* d_ws, size_t ws_size,
                              hipStream_t stream) {
    const float* xb = (const float*)d_in[0];
    const float* yb = (const float*)d_in[1];
    const float* rb = (const float*)d_in[2];
    const float* zb = (const float*)d_in[3];
    const float* W0 = (const float*)d_in[4];
    const float* b0 = (const float*)d_in[5];
    const float* Wm = (const float*)d_in[6];
    const float* bm = (const float*)d_in[7];
    const float* Wo = (const float*)d_in[8];
    const float* bo = (const float*)d_in[9];
    const int* masks = (const int*)d_in[10];

    float* wf = (float*)d_ws;
    int*   wi = (int*)d_ws;

    int n = in_sizes[0];   // N pixels

    cppn_prep<<<1, 512, 0, stream>>>(W0, b0, Wm, bm, Wo, bo, masks, wf, wi);

    // 2048 blocks = 8 blocks/CU; at N=2^22, sweep=2^20 -> exactly 4
    // iterations per thread, no tail (guards stay for generality).
    int nb = (n + TILE - 1) / TILE;
    int blocks = nb < 2048 ? nb : 2048;
    int sweep = blocks * TILE;
    cppn_main<<<blocks, 256, 0, stream>>>(
        xb, yb, rb, (const float4*)zb, wf, wi + 384,
        (float*)d_out, n, sweep);
}

// Round 11
// 289.919 us; speedup vs baseline: 1.0270x; 1.0270x over previous
//
#include <hip/hip_runtime.h>

// FC_CPPN: per-pixel tiny MLP, ALL float32 (inputs, weights, output).
//  d_in[0]=x[N], [1]=y[N], [2]=r[N], [3]=z[N,8], [4]=W0[8,11], [5]=b0[8],
//  [6]=Wm[8,8], [7]=bm[8], [8]=Wo[3,8], [9]=bo[3], [10]=masks[3,4,2] (int)
// out: float32 [N,3]
//
// Scaled-state formulation: u_l = 2^l * out_l.
//   pre_l   = (Wm*2^-l) u_l + bm          (prep stores 3 scaled Wm copies)
//   u_{l+1} = u_l + 2^l * act(pre_l)       (2^l = 1,2,4 -> inline consts)
//   result  = sigmoid((Wo/8) u_3 + bo)
//
// ws float layout:
//   [0,88)    W0 (cols 0..7 pre-scaled by 1/Z_SCALE=0.1)
//   [88,96)   b0
//   [96,288)  Wm*2^-l for l=0,1,2 (64 floats each)
//   [288,296) bm
//   [296,320) Wo/8
//   [320,323) bo
// ws int layout: [384,408) funid[l*8 + natural_column] = activation 0..3
//
// R11 = R9/R10 resubmit (both benches were broker-level infra failures;
// identical-source resubmits succeeded after R3->R4 and R6->R7, and this
// kernel cannot hang: strictly-terminating loop, no barriers/atomics).
// Loop WITHOUT prefetch. R8 proved: (1) a loop desyncs waves and fills
// issue slots (VALUBusy 42->76%) -- the convoy is real; (2) prefetch
// double-buffers don't fit: VGPR=40 forces AGPR spill-moves (v_accvgpr_*,
// VALU insts, no memory traffic) which tripled busy time and ate the gain
// (R1 same: VGPR=44, busy 69%). This is the untested cell: plain
// grid-stride loop, R0's exact 20-VGPR body, no prefetch buffers ->
// desync without spill bloat. 2048 blocks (8/CU), sweep=2^20 divides
// N=2^22 exactly -> 4 iterations, no tail. Numerics bit-identical to R0.
// Critical check: VGPR must stay <=32.

__global__ void cppn_prep(const float* __restrict__ W0,
                          const float* __restrict__ b0,
                          const float* __restrict__ Wm,
                          const float* __restrict__ bm,
                          const float* __restrict__ Wo,
                          const float* __restrict__ bo,
                          const int* __restrict__ masks,
                          float* __restrict__ wf,
                          int* __restrict__ wi) {
    int t = threadIdx.x;
    if (t < 88) {
        int k = t % 11;
        wf[t] = W0[t] * (k < 8 ? 0.1f : 1.0f);      // fold z/Z_SCALE
    } else if (t < 96) {
        wf[t] = b0[t - 88];
    } else if (t < 288) {
        int j = t - 96;
        int l = j >> 6;                              // which scaled copy
        float s = (l == 0) ? 1.0f : (l == 1 ? 0.5f : 0.25f);
        wf[96 + j] = Wm[j & 63] * s;
    } else if (t < 296) {
        wf[t] = bm[t - 288];
    } else if (t < 320) {
        wf[t] = Wo[t - 296] * 0.125f;                // fold /8
    } else if (t < 323) {
        wf[t] = bo[t - 320];
    } else if (t < 323 + 24) {
        int j = t - 323;          // j = l*8 + f*2 + slot  (masks flat [3,4,2])
        // int64-masks hedge: valid int32 masks have every odd entry >= 1;
        // int64-as-int32 has all odd words == 0 (high words, little-endian).
        bool is64 = true;
        for (int q = 1; q < 24; q += 2) is64 = is64 && (masks[q] == 0);
        int c = is64 ? masks[2 * j] : masks[j];      // natural column 0..7
        int l = j >> 3;
        int f = (j & 7) >> 1;                        // activation id
        wi[384 + l * 8 + c] = f;
    }
}

#define PX 2   // pixels per thread per iteration
#define TPB 256
#define TILE (TPB * PX)

__global__ __launch_bounds__(256) void cppn_main(
    const float* __restrict__ xb,
    const float* __restrict__ yb,
    const float* __restrict__ rb,
    const float4* __restrict__ zb,         // 8 f32 per pixel = two float4
    const float* __restrict__ wf,          // ws floats (uniform -> s_load)
    const int* __restrict__ fid,           // funid base (ws ints + 384)
    float* __restrict__ out,
    int n, int sweep) {                    // sweep = gridDim.x * TILE
    int base = blockIdx.x * TILE + threadIdx.x;

#pragma unroll 1
    for (int i0 = base; i0 < n; i0 += sweep) {
        int idx[PX];
        bool ok[PX];
#pragma unroll
        for (int px = 0; px < PX; ++px) {
            idx[px] = i0 + px * TPB;
            ok[px] = idx[px] < n;
        }

        float in[PX][11];
#pragma unroll
        for (int px = 0; px < PX; ++px) {
            int i = ok[px] ? idx[px] : 0;
            float4 z0 = zb[2 * i];
            float4 z1 = zb[2 * i + 1];
            in[px][0] = z0.x; in[px][1] = z0.y; in[px][2] = z0.z; in[px][3] = z0.w;
            in[px][4] = z1.x; in[px][5] = z1.y; in[px][6] = z1.z; in[px][7] = z1.w;
            in[px][8]  = xb[i];
            in[px][9]  = yb[i];
            in[px][10] = rb[i];
        }

        float u[PX][8];
#pragma unroll
        for (int h = 0; h < 8; ++h) {
#pragma unroll
            for (int px = 0; px < PX; ++px) {
                float acc = wf[88 + h];
#pragma unroll
                for (int k = 0; k < 11; ++k)
                    acc = fmaf(wf[h * 11 + k], in[px][k], acc);
                u[px][h] = acc;
            }
        }

#pragma unroll
        for (int l = 0; l < 3; ++l) {
            const float* W = wf + 96 + 64 * l;            // Wm * 2^-l
            const float scale = (l == 0) ? 1.0f : (l == 1 ? 2.0f : 4.0f);
            float p[PX][8];
#pragma unroll
            for (int h = 0; h < 8; ++h) {
#pragma unroll
                for (int px = 0; px < PX; ++px) {
                    float acc = wf[288 + h];
#pragma unroll
                    for (int k = 0; k < 8; ++k)
                        acc = fmaf(W[h * 8 + k], u[px][k], acc);
                    p[px][h] = acc;
                }
            }
#pragma unroll
            for (int h = 0; h < 8; ++h) {
                // wave-uniform activation id -> scalar branch, no divergence;
                // one branch serves PX pixels.
                int f = __builtin_amdgcn_readfirstlane(fid[l * 8 + h]);
                float v[PX];
                if (f == 0) {
#pragma unroll
                    for (int px = 0; px < PX; ++px) v[px] = __sinf(p[px][h]);
                } else if (f == 1) {
#pragma unroll
                    for (int px = 0; px < PX; ++px) {
                        float t = p[px][h];
                        v[px] = 0.3989422804014327f * __expf(-0.5f * t * t);
                    }
                } else if (f == 2) {
#pragma unroll
                    for (int px = 0; px < PX; ++px) {
                        // tanh(t) = 1 - 2/(e^{2t}+1); e=inf -> rcp=0 -> v=1
                        float e = __expf(2.0f * p[px][h]);
                        v[px] = fmaf(-2.0f, __builtin_amdgcn_rcpf(e + 1.0f), 1.0f);
                    }
                } else {
#pragma unroll
                    for (int px = 0; px < PX; ++px) v[px] = p[px][h];
                }
#pragma unroll
                for (int px = 0; px < PX; ++px)
                    u[px][h] = fmaf(scale, v[px], u[px][h]);  // inline-const
            }
        }

#pragma unroll
        for (int j = 0; j < 3; ++j) {
#pragma unroll
            for (int px = 0; px < PX; ++px) {
                float acc = wf[320 + j];
#pragma unroll
                for (int k = 0; k < 8; ++k)
                    acc = fmaf(wf[296 + j * 8 + k], u[px][k], acc);
                float e = __expf(-acc);                        // sigmoid
                float v = __builtin_amdgcn_rcpf(1.0f + e);
                if (ok[px]) out[3 * idx[px] + j] = v;
            }
        }
    }
}

extern "C" void kernel_launch(void* const* d_in, const int* in_sizes, int n_in,
                              void* d_out, int out_size, void* d_ws, size_t ws_size,
                              hipStream_t stream) {
    const float* xb = (const float*)d_in[0];
    const float* yb = (const float*)d_in[1];
    const float* rb = (const float*)d_in[2];
    const float* zb = (const float*)d_in[3];
    const float* W0 = (const float*)d_in[4];
    const float* b0 = (const float*)d_in[5];
    const float* Wm = (const float*)d_in[6];
    const float* bm = (const float*)d_in[7];
    const float* Wo = (const float*)d_in[8];
    const float* bo = (const float*)d_in[9];
    const int* masks = (const int*)d_in[10];

    float* wf = (float*)d_ws;
    int*   wi = (int*)d_ws;

    int n = in_sizes[0];   // N pixels

    cppn_prep<<<1, 512, 0, stream>>>(W0, b0, Wm, bm, Wo, bo, masks, wf, wi);

    // 2048 blocks = 8 blocks/CU; at N=2^22, sweep=2^20 -> exactly 4
    // iterations per thread, no tail (guards stay for generality).
    int nb = (n + TILE - 1) / TILE;
    int blocks = nb < 2048 ? nb : 2048;
    int sweep = blocks * TILE;
    cppn_main<<<blocks, 256, 0, stream>>>(
        xb, yb, rb, (const float4*)zb, wf, wi + 384,
        (float*)d_out, n, sweep);
}

// Round 12
// 265.229 us; speedup vs baseline: 1.1226x; 1.0931x over previous
//
#include <hip/hip_runtime.h>

// FC_CPPN: per-pixel tiny MLP, ALL float32 (inputs, weights, output).
//  d_in[0]=x[N], [1]=y[N], [2]=r[N], [3]=z[N,8], [4]=W0[8,11], [5]=b0[8],
//  [6]=Wm[8,8], [7]=bm[8], [8]=Wo[3,8], [9]=bo[3], [10]=masks[3,4,2] (int)
// out: float32 [N,3]
//
// Scaled-state formulation: u_l = 2^l * out_l.
//   pre_l   = (Wm*2^-l) u_l + bm          (prep stores 3 scaled Wm copies)
//   u_{l+1} = u_l + 2^l * act(pre_l)       (2^l = 1,2,4 -> inline consts)
//   result  = sigmoid((Wo/8) u_3 + bo)
//
// ws float layout:
//   [0,88)    W0 (cols 0..7 pre-scaled by 1/Z_SCALE=0.1)
//   [88,96)   b0
//   [96,288)  Wm*2^-l for l=0,1,2 (64 floats each)
//   [288,296) bm
//   [296,320) Wo/8
//   [320,323) bo
// ws int layout: [384,408) funid[l*8 + natural_column] = activation 0..3
//
// R12: kill cross-iteration weight caching. Ledger: one-shot (R0/R2/R5/R7)
// = 86us, VGPR 20, busy 42% (latency-bound convoy). Loop (R1/R8/R11) =
// 116-156us, VGPR 40-44, busy 69-79% -- identical bloat WITH or WITHOUT
// prefetch buffers, so the loop itself adds ~1650 VALU insts/iter.
// Mechanism fit: compiler hoists the 323 loop-invariant weight VALUES out
// of the loop; they don't fit in SGPRs -> parked in AGPRs (gfx950 unified
// file) -> v_accvgpr_read per use (~608/iter) + unfoldable operands.
// Fix: asm volatile memory clobber at top of each iteration -> weight
// values cannot be cached across iterations; they are re-s_loaded (1.3KB,
// scalar-cache-hot, latency covered by the desynced waves R8/R11 proved).
// Register-promoted locals (in/u/p, address never escapes) are unaffected.
// Numerics bit-identical to R0. Checks: VGPR ~24-28 = theory confirmed;
// VGPR 40 = bloat intrinsic -> declare R0 floor.

__global__ void cppn_prep(const float* __restrict__ W0,
                          const float* __restrict__ b0,
                          const float* __restrict__ Wm,
                          const float* __restrict__ bm,
                          const float* __restrict__ Wo,
                          const float* __restrict__ bo,
                          const int* __restrict__ masks,
                          float* __restrict__ wf,
                          int* __restrict__ wi) {
    int t = threadIdx.x;
    if (t < 88) {
        int k = t % 11;
        wf[t] = W0[t] * (k < 8 ? 0.1f : 1.0f);      // fold z/Z_SCALE
    } else if (t < 96) {
        wf[t] = b0[t - 88];
    } else if (t < 288) {
        int j = t - 96;
        int l = j >> 6;                              // which scaled copy
        float s = (l == 0) ? 1.0f : (l == 1 ? 0.5f : 0.25f);
        wf[96 + j] = Wm[j & 63] * s;
    } else if (t < 296) {
        wf[t] = bm[t - 288];
    } else if (t < 320) {
        wf[t] = Wo[t - 296] * 0.125f;                // fold /8
    } else if (t < 323) {
        wf[t] = bo[t - 320];
    } else if (t < 323 + 24) {
        int j = t - 323;          // j = l*8 + f*2 + slot  (masks flat [3,4,2])
        // int64-masks hedge: valid int32 masks have every odd entry >= 1;
        // int64-as-int32 has all odd words == 0 (high words, little-endian).
        bool is64 = true;
        for (int q = 1; q < 24; q += 2) is64 = is64 && (masks[q] == 0);
        int c = is64 ? masks[2 * j] : masks[j];      // natural column 0..7
        int l = j >> 3;
        int f = (j & 7) >> 1;                        // activation id
        wi[384 + l * 8 + c] = f;
    }
}

#define PX 2   // pixels per thread per iteration
#define TPB 256
#define TILE (TPB * PX)

__global__ __launch_bounds__(256) void cppn_main(
    const float* __restrict__ xb,
    const float* __restrict__ yb,
    const float* __restrict__ rb,
    const float4* __restrict__ zb,         // 8 f32 per pixel = two float4
    const float* __restrict__ wf,          // ws floats (uniform -> s_load)
    const int* __restrict__ fid,           // funid base (ws ints + 384)
    float* __restrict__ out,
    int n, int sweep) {                    // sweep = gridDim.x * TILE
    int base = blockIdx.x * TILE + threadIdx.x;

#pragma unroll 1
    for (int i0 = base; i0 < n; i0 += sweep) {
        // Forbid caching loaded VALUES (esp. the 323 weights) across
        // iterations: without this, the compiler parks them in AGPRs and
        // pays v_accvgpr_read per use (~1650 extra VALU insts/iter --
        // the R1/R8/R11 bloat). Weights get re-s_loaded instead (cheap,
        // scalar-cache-hot; latency hidden by desynced waves).
        asm volatile("" ::: "memory");

        int idx[PX];
        bool ok[PX];
#pragma unroll
        for (int px = 0; px < PX; ++px) {
            idx[px] = i0 + px * TPB;
            ok[px] = idx[px] < n;
        }

        float in[PX][11];
#pragma unroll
        for (int px = 0; px < PX; ++px) {
            int i = ok[px] ? idx[px] : 0;
            float4 z0 = zb[2 * i];
            float4 z1 = zb[2 * i + 1];
            in[px][0] = z0.x; in[px][1] = z0.y; in[px][2] = z0.z; in[px][3] = z0.w;
            in[px][4] = z1.x; in[px][5] = z1.y; in[px][6] = z1.z; in[px][7] = z1.w;
            in[px][8]  = xb[i];
            in[px][9]  = yb[i];
            in[px][10] = rb[i];
        }

        float u[PX][8];
#pragma unroll
        for (int h = 0; h < 8; ++h) {
#pragma unroll
            for (int px = 0; px < PX; ++px) {
                float acc = wf[88 + h];
#pragma unroll
                for (int k = 0; k < 11; ++k)
                    acc = fmaf(wf[h * 11 + k], in[px][k], acc);
                u[px][h] = acc;
            }
        }

#pragma unroll
        for (int l = 0; l < 3; ++l) {
            const float* W = wf + 96 + 64 * l;            // Wm * 2^-l
            const float scale = (l == 0) ? 1.0f : (l == 1 ? 2.0f : 4.0f);
            float p[PX][8];
#pragma unroll
            for (int h = 0; h < 8; ++h) {
#pragma unroll
                for (int px = 0; px < PX; ++px) {
                    float acc = wf[288 + h];
#pragma unroll
                    for (int k = 0; k < 8; ++k)
                        acc = fmaf(W[h * 8 + k], u[px][k], acc);
                    p[px][h] = acc;
                }
            }
#pragma unroll
            for (int h = 0; h < 8; ++h) {
                // wave-uniform activation id -> scalar branch, no divergence;
                // one branch serves PX pixels.
                int f = __builtin_amdgcn_readfirstlane(fid[l * 8 + h]);
                float v[PX];
                if (f == 0) {
#pragma unroll
                    for (int px = 0; px < PX; ++px) v[px] = __sinf(p[px][h]);
                } else if (f == 1) {
#pragma unroll
                    for (int px = 0; px < PX; ++px) {
                        float t = p[px][h];
                        v[px] = 0.3989422804014327f * __expf(-0.5f * t * t);
                    }
                } else if (f == 2) {
#pragma unroll
                    for (int px = 0; px < PX; ++px) {
                        // tanh(t) = 1 - 2/(e^{2t}+1); e=inf -> rcp=0 -> v=1
                        float e = __expf(2.0f * p[px][h]);
                        v[px] = fmaf(-2.0f, __builtin_amdgcn_rcpf(e + 1.0f), 1.0f);
                    }
                } else {
#pragma unroll
                    for (int px = 0; px < PX; ++px) v[px] = p[px][h];
                }
#pragma unroll
                for (int px = 0; px < PX; ++px)
                    u[px][h] = fmaf(scale, v[px], u[px][h]);  // inline-const
            }
        }

#pragma unroll
        for (int j = 0; j < 3; ++j) {
#pragma unroll
            for (int px = 0; px < PX; ++px) {
                float acc = wf[320 + j];
#pragma unroll
                for (int k = 0; k < 8; ++k)
                    acc = fmaf(wf[296 + j * 8 + k], u[px][k], acc);
                float e = __expf(-acc);                        // sigmoid
                float v = __builtin_amdgcn_rcpf(1.0f + e);
                if (ok[px]) out[3 * idx[px] + j] = v;
            }
        }
    }
}

extern "C" void kernel_launch(void* const* d_in, const int* in_sizes, int n_in,
                              void* d_out, int out_size, void* d_ws, size_t ws_size,
                              hipStream_t stream) {
    const float* xb = (const float*)d_in[0];
    const float* yb = (const float*)d_in[1];
    const float* rb = (const float*)d_in[2];
    const float* zb = (const float*)d_in[3];
    const float* W0 = (const float*)d_in[4];
    const float* b0 = (const float*)d_in[5];
    const float* Wm = (const float*)d_in[6];
    const float* bm = (const float*)d_in[7];
    const float* Wo = (const float*)d_in[8];
    const float* bo = (const float*)d_in[9];
    const int* masks = (const int*)d_in[10];

    float* wf = (float*)d_ws;
    int*   wi = (int*)d_ws;

    int n = in_sizes[0];   // N pixels

    cppn_prep<<<1, 512, 0, stream>>>(W0, b0, Wm, bm, Wo, bo, masks, wf, wi);

    // 2048 blocks = 8 blocks/CU; at N=2^22, sweep=2^20 -> exactly 4
    // iterations per thread, no tail (guards stay for generality).
    int nb = (n + TILE - 1) / TILE;
    int blocks = nb < 2048 ? nb : 2048;
    int sweep = blocks * TILE;
    cppn_main<<<blocks, 256, 0, stream>>>(
        xb, yb, rb, (const float4*)zb, wf, wi + 384,
        (float*)d_out, n, sweep);
}